// Round 1
// baseline (100.969 us; speedup 1.0000x reference)
//
#include <hip/hip_runtime.h>

typedef _Float16 f16x8 __attribute__((ext_vector_type(8)));
typedef float f32x4 __attribute__((ext_vector_type(4)));

#define MFMA16(a, b, c) __builtin_amdgcn_mfma_f32_16x16x32_f16(a, b, c, 0, 0, 0)

// ---- ws byte offsets (all 16B aligned) ----
#define OFF_W1   0u        // eW1  512x512 f16 packed (524288 B)
#define OFF_W2   524288u   // eW2  512x128 (131072 B)
#define OFF_W3   655360u   // eW3  128x64  (16384 B)
#define OFF_W4   671744u   // dW1' 64x128  (16384 B)  = (H64 dW1) * w1c/8
#define OFF_W5   688128u   // dW2  128x32  (8192 B)
#define OFF_W6   696320u   // pW'  32x32   (2048 B)   = (H32 pW) * w2c/sqrt(32)
#define OFF_DB1  698368u   // db1' 128 f32 (512 B)    = db1 + w1b*colsum(dW1)
#define OFF_PB   698880u   // pb'  32 f32  (128 B)    = pb  + w2b*colsum(pW)

// Pack W[K][N] (row-major f32) into MFMA-B fragment order:
// dst[((kk*NF + nf)*64 + lane)*8 + j] = W[kk*32 + (lane>>4)*8 + j][nf*16 + (lane&15)]
__device__ inline void packw(int local, int N, const float* __restrict__ W,
                             _Float16* __restrict__ dst) {
  int j = local & 7;
  int lane = (local >> 3) & 63;
  int fi = local >> 9;
  int NF = N >> 4;
  int nf = fi % NF;
  int kk = fi / NF;
  int k = kk * 32 + ((lane >> 4) << 3) + j;
  int n = (nf << 4) + (lane & 15);
  dst[local] = (_Float16)W[k * N + n];
}

// Same, but source = scale * (H_K @ W),  H[k][m] = (-1)^popc(k&m)
__device__ inline void packh(int local, int N, int K, const float* __restrict__ W,
                             _Float16* __restrict__ dst, float scale) {
  int j = local & 7;
  int lane = (local >> 3) & 63;
  int fi = local >> 9;
  int NF = N >> 4;
  int nf = fi % NF;
  int kk = fi / NF;
  int k = kk * 32 + ((lane >> 4) << 3) + j;
  int n = (nf << 4) + (lane & 15);
  float s = 0.f;
  for (int m = 0; m < K; ++m) {
    float v = W[m * N + n];
    s += (__popc(k & m) & 1) ? -v : v;
  }
  dst[local] = (_Float16)(s * scale);
}

extern "C" __global__ __launch_bounds__(256) void prep_kernel(
    const float* __restrict__ eW1, const float* __restrict__ eW2,
    const float* __restrict__ eW3, const float* __restrict__ dW1,
    const float* __restrict__ dW2, const float* __restrict__ pW,
    const float* __restrict__ w1c, const float* __restrict__ w1b,
    const float* __restrict__ w2c, const float* __restrict__ w2b,
    const float* __restrict__ db1, const float* __restrict__ pb,
    char* __restrict__ ws) {
  int idx = blockIdx.x * 256 + threadIdx.x;
  if (idx < 262144) {
    packw(idx, 512, eW1, (_Float16*)(ws + OFF_W1));
  } else if (idx < 327680) {
    packw(idx - 262144, 128, eW2, (_Float16*)(ws + OFF_W2));
  } else if (idx < 335872) {
    packw(idx - 327680, 64, eW3, (_Float16*)(ws + OFF_W3));
  } else if (idx < 344064) {
    packh(idx - 335872, 128, 64, dW1, (_Float16*)(ws + OFF_W4), w1c[0] * 0.125f);
  } else if (idx < 348160) {
    packw(idx - 344064, 32, dW2, (_Float16*)(ws + OFF_W5));
  } else if (idx < 349184) {
    packh(idx - 348160, 32, 32, pW, (_Float16*)(ws + OFF_W6),
          w2c[0] * 0.17677669529663687f);  // 1/sqrt(32)
  } else if (idx < 349312) {
    int n = idx - 349184;
    float s = 0.f;
    for (int m = 0; m < 64; ++m) s += dW1[m * 128 + n];
    ((float*)(ws + OFF_DB1))[n] = db1[n] + w1b[0] * s;
  } else if (idx < 349344) {
    int n = idx - 349312;
    float s = 0.f;
    for (int m = 0; m < 32; ++m) s += pW[m * 32 + n];
    ((float*)(ws + OFF_PB))[n] = pb[n] + w2b[0] * s;
  }
}

// ---- fused main kernel ----
// 32 rows per WG, 512 threads = 8 waves, two 32KB LDS h-buffers (ping-pong).
// LDS element layout: XOR-swizzled row-major, LD=512 f16.
// unit = col>>3 (16B units, 64/row); swizzled unit = unit ^ (row&7).
// A-fragment reads (16 lanes, same unit, rows 0..15) land 2 lanes/bank -> free.
__device__ inline int hidx(int row, int col) {
  return (row << 9) + ((((col >> 3) ^ (row & 7)) << 3) | (col & 7));
}

__device__ inline f16x8 afrag(const _Float16* __restrict__ h, int row, int col) {
  return *(const f16x8*)(h + hidx(row, col));  // col is a multiple of 8 -> 16B aligned
}

// Generic layer: out[32][16*NF] = act(in[32][KSTEPS*32] @ W + bias)
// wave w owns column fragment nf=w (waves w>=NF idle).
template <int KSTEPS, bool RELU>
__device__ inline void mlayer(const _Float16* __restrict__ hin, _Float16* __restrict__ hout,
                              const f16x8* __restrict__ Wp, const float* __restrict__ bias,
                              int NF, int w, int lane, int g, int rr) {
  if (w < NF) {
    const int nf = w;
    f32x4 acc0 = {0.f, 0.f, 0.f, 0.f};
    f32x4 acc1 = {0.f, 0.f, 0.f, 0.f};
#pragma unroll
    for (int kk = 0; kk < KSTEPS; ++kk) {
      f16x8 a0 = afrag(hin, rr, kk * 32 + g * 8);
      f16x8 a1 = afrag(hin, 16 + rr, kk * 32 + g * 8);
      f16x8 b = Wp[(kk * NF + nf) * 64 + lane];
      acc0 = MFMA16(a0, b, acc0);
      acc1 = MFMA16(a1, b, acc1);
    }
    const int n = nf * 16 + rr;
    const float bv = bias[n];
#pragma unroll
    for (int i = 0; i < 4; ++i) {
      float v0 = acc0[i] + bv;
      float v1 = acc1[i] + bv;
      if (RELU) {
        v0 = fmaxf(v0, 0.f);
        v1 = fmaxf(v1, 0.f);
      }
      hout[hidx(g * 4 + i, n)] = (_Float16)v0;
      hout[hidx(16 + g * 4 + i, n)] = (_Float16)v1;
    }
  }
}

extern "C" __global__ __launch_bounds__(512, 4) void fused_kernel(
    const float* __restrict__ x, const float* __restrict__ dw1,
    const float* __restrict__ dw2, const float* __restrict__ eb1,
    const float* __restrict__ eb2, const float* __restrict__ eb3,
    const float* __restrict__ db2, const char* __restrict__ ws,
    float* __restrict__ out) {
  __shared__ __align__(16) _Float16 hA[32 * 512];
  __shared__ __align__(16) _Float16 hB[32 * 512];

  const int tid = threadIdx.x;
  const int blk = blockIdx.x;
  const int lane = tid & 63;
  const int w = tid >> 6;
  const int g = lane >> 4;
  const int rr = lane & 15;

  // ---- phase 0: downsample x -> h0 = concat(R, Z) in fp16 ----
  {
    const float d10 = dw1[0], d11 = dw1[1], d12 = dw1[2], d13 = dw1[3];
    const float d20 = dw2[0], d21 = dw2[1], d22 = dw2[2], d23 = dw2[3];
    const float4* __restrict__ xv = (const float4*)(x + (size_t)blk * 32 * 1024);
#pragma unroll
    for (int i = 0; i < 16; ++i) {
      int f = tid + i * 512;  // f = r*256 + t
      int r = f >> 8;
      int t = f & 255;
      float4 v = xv[f];
      float R = v.x * d10 + v.y * d11 + v.z * d12 + v.w * d13;
      float Z = v.x * d20 + v.y * d21 + v.z * d22 + v.w * d23;
      hA[hidx(r, t)] = (_Float16)R;
      hA[hidx(r, 256 + t)] = (_Float16)Z;
    }
  }
  __syncthreads();

  // ---- L1: h1 = relu(h0 @ eW1 + eb1), K=512 N=512; wave w owns cols [w*64, w*64+64) ----
  {
    const f16x8* __restrict__ W1 = (const f16x8*)(ws + OFF_W1);
    f32x4 acc[2][4];
#pragma unroll
    for (int m = 0; m < 2; ++m)
#pragma unroll
      for (int n = 0; n < 4; ++n) acc[m][n] = (f32x4){0.f, 0.f, 0.f, 0.f};
    const int nf0 = w * 4;
    for (int kk = 0; kk < 16; ++kk) {
      f16x8 a0 = afrag(hA, rr, kk * 32 + g * 8);
      f16x8 a1 = afrag(hA, 16 + rr, kk * 32 + g * 8);
#pragma unroll
      for (int nf = 0; nf < 4; ++nf) {
        f16x8 b = W1[(kk * 32 + nf0 + nf) * 64 + lane];
        acc[0][nf] = MFMA16(a0, b, acc[0][nf]);
        acc[1][nf] = MFMA16(a1, b, acc[1][nf]);
      }
    }
#pragma unroll
    for (int nf = 0; nf < 4; ++nf) {
      const int n = (nf0 + nf) * 16 + rr;
      const float bv = eb1[n];
#pragma unroll
      for (int i = 0; i < 4; ++i) {
        float v0 = fmaxf(acc[0][nf][i] + bv, 0.f);
        float v1 = fmaxf(acc[1][nf][i] + bv, 0.f);
        hB[hidx(g * 4 + i, n)] = (_Float16)v0;
        hB[hidx(16 + g * 4 + i, n)] = (_Float16)v1;
      }
    }
  }
  __syncthreads();

  // L2: h2 = relu(h1 @ eW2 + eb2), K=512 N=128
  mlayer<16, true>(hB, hA, (const f16x8*)(ws + OFF_W2), eb2, 8, w, lane, g, rr);
  __syncthreads();
  // L3: h3 = h2 @ eW3 + eb3 (FWHT folded into next layer), K=128 N=64
  mlayer<4, false>(hA, hB, (const f16x8*)(ws + OFF_W3), eb3, 4, w, lane, g, rr);
  __syncthreads();
  // L4: h4 = relu(h3 @ dW1' + db1'), K=64 N=128
  mlayer<2, true>(hB, hA, (const f16x8*)(ws + OFF_W4), (const float*)(ws + OFF_DB1), 8, w,
                  lane, g, rr);
  __syncthreads();
  // L5: h5 = h4 @ dW2 + db2, K=128 N=32
  mlayer<4, false>(hA, hB, (const f16x8*)(ws + OFF_W5), db2, 2, w, lane, g, rr);
  __syncthreads();

  // ---- L6: out = h5 @ pW' + pb', K=32 N=32, f32 global store ----
  {
    const f16x8* __restrict__ W6 = (const f16x8*)(ws + OFF_W6);
    const float* __restrict__ pbp = (const float*)(ws + OFF_PB);
    if (w < 2) {
      const int nf = w;
      f32x4 acc0 = {0.f, 0.f, 0.f, 0.f};
      f32x4 acc1 = {0.f, 0.f, 0.f, 0.f};
      f16x8 a0 = afrag(hB, rr, g * 8);
      f16x8 a1 = afrag(hB, 16 + rr, g * 8);
      f16x8 b = W6[nf * 64 + lane];
      acc0 = MFMA16(a0, b, acc0);
      acc1 = MFMA16(a1, b, acc1);
      const int n = nf * 16 + rr;
      const float bv = pbp[n];
      const size_t rbase = (size_t)blk * 32;
#pragma unroll
      for (int i = 0; i < 4; ++i) {
        out[(rbase + g * 4 + i) * 32 + n] = acc0[i] + bv;
        out[(rbase + 16 + g * 4 + i) * 32 + n] = acc1[i] + bv;
      }
    }
  }
}

extern "C" void kernel_launch(void* const* d_in, const int* in_sizes, int n_in,
                              void* d_out, int out_size, void* d_ws, size_t ws_size,
                              hipStream_t stream) {
  const float* x = (const float*)d_in[0];
  const float* dw1 = (const float*)d_in[1];
  const float* dw2 = (const float*)d_in[2];
  const float* eW1 = (const float*)d_in[3];
  const float* eb1 = (const float*)d_in[4];
  const float* eW2 = (const float*)d_in[5];
  const float* eb2 = (const float*)d_in[6];
  const float* eW3 = (const float*)d_in[7];
  const float* eb3 = (const float*)d_in[8];
  const float* w1c = (const float*)d_in[9];
  const float* w1b = (const float*)d_in[10];
  const float* dW1 = (const float*)d_in[11];
  const float* db1 = (const float*)d_in[12];
  const float* dW2 = (const float*)d_in[13];
  const float* db2 = (const float*)d_in[14];
  const float* w2c = (const float*)d_in[15];
  const float* w2b = (const float*)d_in[16];
  const float* pW = (const float*)d_in[17];
  const float* pb = (const float*)d_in[18];
  char* ws = (char*)d_ws;
  float* out = (float*)d_out;

  prep_kernel<<<dim3(1365), dim3(256), 0, stream>>>(eW1, eW2, eW3, dW1, dW2, pW, w1c, w1b,
                                                    w2c, w2b, db1, pb, ws);
  fused_kernel<<<dim3(2048), dim3(512), 0, stream>>>(x, dw1, dw2, eb1, eb2, eb3, db2, ws,
                                                     out);
}